// Round 5
// baseline (321.517 us; speedup 1.0000x reference)
//
#include <hip/hip_runtime.h>

// MHA: out = softmax((XWq)(XWk)^T/8)(XWv) Wo ; B=2, L=2048, D=1024, H=16, dk=64
// fp32 in/out, f16 MFMA internally, f32 accumulation.

typedef _Float16 h16;
typedef _Float16 half8 __attribute__((ext_vector_type(8)));
typedef _Float16 half4 __attribute__((ext_vector_type(4)));
typedef float f32x4 __attribute__((ext_vector_type(4)));

#define D_MODEL 1024
#define N_HEADS 16
#define D_HEAD  64
#define SEQ_L   2048
// fold 1/sqrt(dk) and log2(e) into Wq so scores are in exp2 units
#define QSCALE   0.18033688011f
#define DEFER_TH 10.0f  // exp2 units; P bounded by 2^10=1024 (f16-safe)

// async global->LDS, 16B per lane, wave-uniform LDS base (HW adds lane*16)
#define GLD16(gp, lp)                                                  \
  __builtin_amdgcn_global_load_lds(                                    \
      (const __attribute__((address_space(1))) void*)(gp),             \
      (__attribute__((address_space(3))) void*)(lp), 16, 0, 0)

// ---------------------------------------------------------------------------
// conversion kernels
// ---------------------------------------------------------------------------
struct XArgs { const float* src[3]; h16* dst[3]; };

__global__ __launch_bounds__(256) void convert_x(XArgs xa) {
  const float* src = xa.src[blockIdx.y];
  h16* dst = xa.dst[blockIdx.y];
  size_t i = ((size_t)blockIdx.x * 256 + threadIdx.x) * 8;
  float4 a = *reinterpret_cast<const float4*>(src + i);
  float4 b = *reinterpret_cast<const float4*>(src + i + 4);
  half8 o = {(h16)a.x, (h16)a.y, (h16)a.z, (h16)a.w,
             (h16)b.x, (h16)b.y, (h16)b.z, (h16)b.w};
  *reinterpret_cast<half8*>(dst + i) = o;
}

struct WArgs { const float* w[4]; h16* wt[4]; };

__global__ __launch_bounds__(256) void convert_wt(WArgs wa) {
  int z = blockIdx.z;
  const float* W = wa.w[z];
  h16* Wt = wa.wt[z];
  float scale = (z == 0) ? QSCALE : 1.0f;
  int k0 = blockIdx.x * 64, n0 = blockIdx.y * 64;
  __shared__ h16 T[64][65];
  int tid = threadIdx.x;
#pragma unroll
  for (int q = 0; q < 4; q++) {
    int fi = q * 256 + tid;
    int r = fi >> 4, c4 = (fi & 15) * 4;
    float4 v = *reinterpret_cast<const float4*>(W + (size_t)(k0 + r) * D_MODEL + n0 + c4);
    T[c4 + 0][r] = (h16)(v.x * scale);
    T[c4 + 1][r] = (h16)(v.y * scale);
    T[c4 + 2][r] = (h16)(v.z * scale);
    T[c4 + 3][r] = (h16)(v.w * scale);
  }
  __syncthreads();
#pragma unroll
  for (int q = 0; q < 2; q++) {
    int fi = q * 256 + tid;
    int r = fi >> 3, g = fi & 7;
    half8 o;
#pragma unroll
    for (int j = 0; j < 8; j++) o[j] = T[r][g * 8 + j];
    *reinterpret_cast<half8*>(Wt + (size_t)(n0 + r) * D_MODEL + k0 + g * 8) = o;
  }
}

__global__ __launch_bounds__(256) void convert_bq(const float* bq, float* bqs) {
  int i = blockIdx.x * 256 + threadIdx.x;
  if (i < D_MODEL) bqs[i] = bq[i] * QSCALE;
}

// ---------------------------------------------------------------------------
// f16 GEMM: 128xBN tile, BK=32, global_load_lds x16B, linear LDS (64B rows),
// 4 waves (2x2). mode 0: f16 natural; mode 1: f16 [b][h][d][L]; mode 2: f32.
// Each wave stages BN/4 B-rows: global rows n0 + w*(BN/4) + ... (MUST match
// the LDS destination rows w*(BN/4)...; round-3 bug was w*(BN/8) here).
// ---------------------------------------------------------------------------
template <int BN>
__device__ __forceinline__ void gemm_body(const h16* __restrict__ A,
                                          const h16* __restrict__ Bt,
                                          const float* __restrict__ bias,
                                          h16* __restrict__ outh,
                                          float* __restrict__ outf,
                                          int mode) {
  constexpr int JT = BN / 32;  // j-tiles per wave
  __shared__ __align__(16) h16 As[128 * 32];
  __shared__ __align__(16) h16 Bs[BN * 32];
  const int tid = threadIdx.x;
  const int lane = tid & 63;
  const int w = tid >> 6;
  const int wm = w >> 1, wn = w & 1;
  const int cl = lane & 15, s = lane >> 4;
  const int m0 = blockIdx.x * 128;
  const int n0 = blockIdx.y * BN;
  const int lr = lane >> 2, lg = lane & 3;

  const f32x4 zero = {0.f, 0.f, 0.f, 0.f};
  f32x4 acc[4][JT];
#pragma unroll
  for (int i = 0; i < 4; i++)
#pragma unroll
    for (int j = 0; j < JT; j++) acc[i][j] = zero;

  const h16* aw = A + (size_t)(m0 + w * 32) * D_MODEL;
  const h16* bw = Bt + (size_t)(n0 + w * (BN / 4)) * D_MODEL;

  for (int k0 = 0; k0 < D_MODEL; k0 += 32) {
#pragma unroll
    for (int issue = 0; issue < 2; issue++) {
      GLD16(aw + (size_t)(issue * 16 + lr) * D_MODEL + k0 + lg * 8,
            As + (w * 32 + issue * 16) * 32);
    }
    if (BN == 128) {
#pragma unroll
      for (int issue = 0; issue < 2; issue++)
        GLD16(bw + (size_t)(issue * 16 + lr) * D_MODEL + k0 + lg * 8,
              Bs + (w * 32 + issue * 16) * 32);
    } else {
      GLD16(bw + (size_t)lr * D_MODEL + k0 + lg * 8, Bs + (w * 16) * 32);
    }
    __syncthreads();
    half8 af[4], bf[JT];
#pragma unroll
    for (int i = 0; i < 4; i++)
      af[i] = *reinterpret_cast<const half8*>(As + (wm * 64 + i * 16 + cl) * 32 + s * 8);
#pragma unroll
    for (int j = 0; j < JT; j++)
      bf[j] = *reinterpret_cast<const half8*>(Bs + (wn * (BN / 2) + j * 16 + cl) * 32 + s * 8);
    __builtin_amdgcn_s_setprio(1);
#pragma unroll
    for (int i = 0; i < 4; i++)
#pragma unroll
      for (int j = 0; j < JT; j++)
        acc[i][j] = __builtin_amdgcn_mfma_f32_16x16x32_f16(af[i], bf[j], acc[i][j], 0, 0, 0);
    __builtin_amdgcn_s_setprio(0);
    __syncthreads();
  }

#pragma unroll
  for (int i = 0; i < 4; i++)
#pragma unroll
    for (int j = 0; j < JT; j++) {
      int c = n0 + wn * (BN / 2) + j * 16 + cl;
      float bv = bias[c];
      int mb = m0 + wm * 64 + i * 16 + s * 4;
      if (mode == 0) {
#pragma unroll
        for (int r = 0; r < 4; r++)
          outh[(size_t)(mb + r) * D_MODEL + c] = (h16)(acc[i][j][r] + bv);
      } else if (mode == 1) {
        int b = mb >> 11, l = mb & 2047;
        int h = c >> 6, d = c & 63;
        half4 o = {(h16)(acc[i][j][0] + bv), (h16)(acc[i][j][1] + bv),
                   (h16)(acc[i][j][2] + bv), (h16)(acc[i][j][3] + bv)};
        *reinterpret_cast<half4*>(outh + (((size_t)(b * N_HEADS + h) * D_HEAD + d) * SEQ_L + l)) = o;
      } else {
#pragma unroll
        for (int r = 0; r < 4; r++)
          outf[(size_t)(mb + r) * D_MODEL + c] = acc[i][j][r] + bv;
      }
    }
}

struct ProjArgs {
  const h16* A[3];
  const h16* W[3];
  const float* b[3];
  h16* out[3];
};

__global__ __launch_bounds__(256) void proj_kernel(ProjArgs pa) {
  int z = blockIdx.z;
  gemm_body<128>(pa.A[z], pa.W[z], pa.b[z], pa.out[z], nullptr, (z == 2) ? 1 : 0);
}

__global__ __launch_bounds__(256) void out_kernel(const h16* __restrict__ A,
                                                  const h16* __restrict__ Wt,
                                                  const float* __restrict__ b,
                                                  float* __restrict__ out) {
  gemm_body<64>(A, Wt, b, nullptr, out, 2);
}

// ---------------------------------------------------------------------------
// Flash attention, no K/V staging (K/V tiles are L1/L2-resident), no barriers.
// 512 blocks (XCD-remapped: each XCD owns 4 heads), 4 waves, 32 q-rows/wave.
// Only P goes through LDS (wave-private 8KB). Scores in exp2 units.
// ---------------------------------------------------------------------------
__global__ __launch_bounds__(256) void attn_kernel(const h16* __restrict__ Qh,
                                                   const h16* __restrict__ Kh,
                                                   const h16* __restrict__ Vt,
                                                   h16* __restrict__ ctx) {
  __shared__ __align__(16) char Ps[32768];
  const int tid = threadIdx.x;
  const int lane = tid & 63;
  const int w = tid >> 6;
  char* Pw = Ps + w * 8192;
  // XCD-aware remap (8 XCDs, id%8 = xcd): xcd owns bh in [4*xcd, 4*xcd+4)
  int lid = blockIdx.x;
  int xcd = lid & 7, slot = lid >> 3;
  int bh = xcd * 4 + (slot & 3);
  int qt = slot >> 2;
  const int b = bh >> 4, h = bh & 15;
  const int q0 = qt * 128 + w * 32;
  const int cl = lane & 15, s = lane >> 4;

  const h16* Kb = Kh + (size_t)b * SEQ_L * D_MODEL + h * D_HEAD;
  const h16* Vb = Vt + (size_t)bh * D_HEAD * SEQ_L;

  // hoist Q fragments
  half8 qf[2][2];
#pragma unroll
  for (int qr = 0; qr < 2; qr++)
#pragma unroll
    for (int kk = 0; kk < 2; kk++)
      qf[qr][kk] = *reinterpret_cast<const half8*>(
          Qh + (size_t)(b * SEQ_L + q0 + qr * 16 + cl) * D_MODEL + h * D_HEAD + kk * 32 + s * 8);

  const f32x4 zero = {0.f, 0.f, 0.f, 0.f};
  f32x4 acc[2][4];
#pragma unroll
  for (int qr = 0; qr < 2; qr++)
#pragma unroll
    for (int td = 0; td < 4; td++) acc[qr][td] = zero;
  float mrow[2][4], lrow[2][4];
#pragma unroll
  for (int qr = 0; qr < 2; qr++)
#pragma unroll
    for (int rg = 0; rg < 4; rg++) { mrow[qr][rg] = -INFINITY; lrow[qr][rg] = 0.f; }

  for (int kv0 = 0; kv0 < SEQ_L; kv0 += 128) {
    // ---- QK^T straight from global K (L1-resident tile) ----
    f32x4 sc[2][8];
    const h16* Kt = Kb + (size_t)(kv0 + cl) * D_MODEL + s * 8;
#pragma unroll
    for (int t = 0; t < 8; t++) {
      half8 bf0 = *reinterpret_cast<const half8*>(Kt + (size_t)t * 16 * D_MODEL);
      half8 bf1 = *reinterpret_cast<const half8*>(Kt + (size_t)t * 16 * D_MODEL + 32);
      __builtin_amdgcn_s_setprio(1);
      sc[0][t] = __builtin_amdgcn_mfma_f32_16x16x32_f16(qf[0][0], bf0, zero, 0, 0, 0);
      sc[0][t] = __builtin_amdgcn_mfma_f32_16x16x32_f16(qf[0][1], bf1, sc[0][t], 0, 0, 0);
      sc[1][t] = __builtin_amdgcn_mfma_f32_16x16x32_f16(qf[1][0], bf0, zero, 0, 0, 0);
      sc[1][t] = __builtin_amdgcn_mfma_f32_16x16x32_f16(qf[1][1], bf1, sc[1][t], 0, 0, 0);
      __builtin_amdgcn_s_setprio(0);
    }

    // ---- online softmax, exp2 units, defer-rescale (T13) ----
    float ml[2][4];
    bool cok = true;
#pragma unroll
    for (int qr = 0; qr < 2; qr++)
#pragma unroll
      for (int rg = 0; rg < 4; rg++) {
        float m = sc[qr][0][rg];
#pragma unroll
        for (int t = 1; t < 8; t++) m = fmaxf(m, sc[qr][t][rg]);
#pragma unroll
        for (int msk = 1; msk < 16; msk <<= 1) m = fmaxf(m, __shfl_xor(m, msk));
        ml[qr][rg] = m;
        cok = cok && (m <= mrow[qr][rg] + DEFER_TH);
      }
    if (!__all(cok)) {
#pragma unroll
      for (int qr = 0; qr < 2; qr++)
#pragma unroll
        for (int rg = 0; rg < 4; rg++) {
          float mn = fmaxf(mrow[qr][rg], ml[qr][rg]);
          float al = exp2f(mrow[qr][rg] - mn);
          mrow[qr][rg] = mn;
          lrow[qr][rg] *= al;
#pragma unroll
          for (int td = 0; td < 4; td++) acc[qr][td][rg] *= al;
        }
    }
#pragma unroll
    for (int qr = 0; qr < 2; qr++)
#pragma unroll
      for (int rg = 0; rg < 4; rg++) {
        float rs = 0.f;
        int pr = qr * 16 + s * 4 + rg;
        int swz = ((s & 3) << 5) ^ ((rg & 1) << 7);
#pragma unroll
        for (int t = 0; t < 8; t++) {
          float p = exp2f(sc[qr][t][rg] - mrow[qr][rg]);
          rs += p;
          int pc = t * 16 + cl;
          *reinterpret_cast<h16*>(Pw + pr * 256 + ((pc * 2) ^ swz)) = (h16)p;
        }
#pragma unroll
        for (int msk = 1; msk < 16; msk <<= 1) rs += __shfl_xor(rs, msk);
        lrow[qr][rg] += rs;
      }

    // ---- PV: P from LDS, V straight from global V^T (L1-resident tile) ----
#pragma unroll
    for (int kvs = 0; kvs < 4; kvs++) {
      half8 pf[2];
#pragma unroll
      for (int qr = 0; qr < 2; qr++) {
        int pr = qr * 16 + cl;
        pf[qr] = *reinterpret_cast<const half8*>(
            Pw + pr * 256 + ((((kvs * 4 + s) << 4) ^ (((pr >> 2) & 3) << 5)) ^ ((pr & 1) << 7)));
      }
      const h16* Vg = Vb + kv0 + kvs * 32 + s * 8;
#pragma unroll
      for (int td = 0; td < 4; td++) {
        half8 vf = *reinterpret_cast<const half8*>(Vg + (size_t)(td * 16 + cl) * SEQ_L);
        __builtin_amdgcn_s_setprio(1);
        acc[0][td] = __builtin_amdgcn_mfma_f32_16x16x32_f16(pf[0], vf, acc[0][td], 0, 0, 0);
        acc[1][td] = __builtin_amdgcn_mfma_f32_16x16x32_f16(pf[1], vf, acc[1][td], 0, 0, 0);
        __builtin_amdgcn_s_setprio(0);
      }
    }
  }

  // ---- write ctx f16 natural [b*L + q][h*64 + d] ----
#pragma unroll
  for (int qr = 0; qr < 2; qr++)
#pragma unroll
    for (int td = 0; td < 4; td++)
#pragma unroll
      for (int rg = 0; rg < 4; rg++) {
        int row = q0 + qr * 16 + s * 4 + rg;
        int d = td * 16 + cl;
        float v = acc[qr][td][rg] / lrow[qr][rg];
        ctx[(size_t)(b * SEQ_L + row) * D_MODEL + h * D_HEAD + d] = (h16)v;
      }
}

// ---------------------------------------------------------------------------
extern "C" void kernel_launch(void* const* d_in, const int* in_sizes, int n_in,
                              void* d_out, int out_size, void* d_ws, size_t ws_size,
                              hipStream_t stream) {
  const float* Q = (const float*)d_in[0];
  const float* K = (const float*)d_in[1];
  const float* V = (const float*)d_in[2];
  const float* Wq = (const float*)d_in[3];
  const float* bq = (const float*)d_in[4];
  const float* Wk = (const float*)d_in[5];
  const float* bk = (const float*)d_in[6];
  const float* Wv = (const float*)d_in[7];
  const float* bv = (const float*)d_in[8];
  const float* Wo = (const float*)d_in[9];
  const float* bo = (const float*)d_in[10];
  float* out = (float*)d_out;

  char* ws = (char*)d_ws;
  const size_t MB = 1024 * 1024;
  h16* Xh[3] = {(h16*)(ws), (h16*)(ws + 8 * MB), (h16*)(ws + 16 * MB)};
  h16* Wt[4] = {(h16*)(ws + 24 * MB), (h16*)(ws + 26 * MB),
                (h16*)(ws + 28 * MB), (h16*)(ws + 30 * MB)};
  h16* Qh = (h16*)(ws + 32 * MB);
  h16* Kh = (h16*)(ws + 40 * MB);
  h16* Vt = (h16*)(ws + 48 * MB);
  float* bqs = (float*)(ws + 56 * MB);
  h16* ctx = Xh[0];  // Xh[0] dead after projections

  XArgs xa;
  xa.src[0] = Q; xa.src[1] = K; xa.src[2] = V;
  xa.dst[0] = Xh[0]; xa.dst[1] = Xh[1]; xa.dst[2] = Xh[2];
  convert_x<<<dim3(2048, 3), 256, 0, stream>>>(xa);

  WArgs wa;
  wa.w[0] = Wq; wa.w[1] = Wk; wa.w[2] = Wv; wa.w[3] = Wo;
  wa.wt[0] = Wt[0]; wa.wt[1] = Wt[1]; wa.wt[2] = Wt[2]; wa.wt[3] = Wt[3];
  convert_wt<<<dim3(16, 16, 4), 256, 0, stream>>>(wa);
  convert_bq<<<dim3(4), 256, 0, stream>>>(bq, bqs);

  ProjArgs pa;
  pa.A[0] = Xh[0]; pa.A[1] = Xh[1]; pa.A[2] = Xh[2];
  pa.W[0] = Wt[0]; pa.W[1] = Wt[1]; pa.W[2] = Wt[2];
  pa.b[0] = bqs;   pa.b[1] = bk;    pa.b[2] = bv;
  pa.out[0] = Qh;  pa.out[1] = Kh;  pa.out[2] = Vt;
  proj_kernel<<<dim3(32, 8, 3), 256, 0, stream>>>(pa);

  attn_kernel<<<dim3(512), 256, 0, stream>>>(Qh, Kh, Vt, ctx);

  out_kernel<<<dim3(32, 16), 256, 0, stream>>>(ctx, Wt[3], bo, out);
}

// Round 6
// 219.606 us; speedup vs baseline: 1.4641x; 1.4641x over previous
//
#include <hip/hip_runtime.h>

// MHA: out = softmax((XWq)(XWk)^T/8)(XWv) Wo ; B=2, L=2048, D=1024, H=16, dk=64
// fp32 in/out, f16 MFMA internally, f32 accumulation.

typedef _Float16 h16;
typedef _Float16 half8 __attribute__((ext_vector_type(8)));
typedef _Float16 half4 __attribute__((ext_vector_type(4)));
typedef float f32x4 __attribute__((ext_vector_type(4)));

#define D_MODEL 1024
#define N_HEADS 16
#define D_HEAD  64
#define SEQ_L   2048
// fold 1/sqrt(dk) and log2(e) into Wq so scores are in exp2 units
#define QSCALE   0.18033688011f
#define DEFER_TH 10.0f  // exp2 units; P bounded by 2^10=1024 (f16-safe)

// async global->LDS, 16B per lane, wave-uniform LDS base (HW adds lane*16)
#define GLD16(gp, lp)                                                  \
  __builtin_amdgcn_global_load_lds(                                    \
      (const __attribute__((address_space(1))) void*)(gp),             \
      (__attribute__((address_space(3))) void*)(lp), 16, 0, 0)

// ---------------------------------------------------------------------------
// conversion kernels
// ---------------------------------------------------------------------------
struct XArgs { const float* src[3]; h16* dst[3]; };

__global__ __launch_bounds__(256) void convert_x(XArgs xa) {
  const float* src = xa.src[blockIdx.y];
  h16* dst = xa.dst[blockIdx.y];
  size_t i = ((size_t)blockIdx.x * 256 + threadIdx.x) * 8;
  float4 a = *reinterpret_cast<const float4*>(src + i);
  float4 b = *reinterpret_cast<const float4*>(src + i + 4);
  half8 o = {(h16)a.x, (h16)a.y, (h16)a.z, (h16)a.w,
             (h16)b.x, (h16)b.y, (h16)b.z, (h16)b.w};
  *reinterpret_cast<half8*>(dst + i) = o;
}

struct WArgs { const float* w[4]; h16* wt[4]; };

__global__ __launch_bounds__(256) void convert_wt(WArgs wa) {
  int z = blockIdx.z;
  const float* W = wa.w[z];
  h16* Wt = wa.wt[z];
  float scale = (z == 0) ? QSCALE : 1.0f;
  int k0 = blockIdx.x * 64, n0 = blockIdx.y * 64;
  __shared__ h16 T[64][65];
  int tid = threadIdx.x;
#pragma unroll
  for (int q = 0; q < 4; q++) {
    int fi = q * 256 + tid;
    int r = fi >> 4, c4 = (fi & 15) * 4;
    float4 v = *reinterpret_cast<const float4*>(W + (size_t)(k0 + r) * D_MODEL + n0 + c4);
    T[c4 + 0][r] = (h16)(v.x * scale);
    T[c4 + 1][r] = (h16)(v.y * scale);
    T[c4 + 2][r] = (h16)(v.z * scale);
    T[c4 + 3][r] = (h16)(v.w * scale);
  }
  __syncthreads();
#pragma unroll
  for (int q = 0; q < 2; q++) {
    int fi = q * 256 + tid;
    int r = fi >> 3, g = fi & 7;
    half8 o;
#pragma unroll
    for (int j = 0; j < 8; j++) o[j] = T[r][g * 8 + j];
    *reinterpret_cast<half8*>(Wt + (size_t)(n0 + r) * D_MODEL + k0 + g * 8) = o;
  }
}

__global__ __launch_bounds__(256) void convert_bq(const float* bq, float* bqs) {
  int i = blockIdx.x * 256 + threadIdx.x;
  if (i < D_MODEL) bqs[i] = bq[i] * QSCALE;
}

// ---------------------------------------------------------------------------
// f16 GEMM: 128xBN tile, BK=32, global_load_lds x16B, linear LDS (64B rows),
// 4 waves (2x2). Each wave stages BN/4 B-rows (global row base n0 + w*(BN/4)).
// mode 0: f16 natural [m][n]
// mode 1: f16 [b][h][d][L] (V^T, half4 along L)
// mode 2: f32 natural
// mode 3: f16 K pre-swizzled [b][h][l][64], element d at ((d>>3)^(l&7))*8+(d&7)
// ---------------------------------------------------------------------------
template <int BN>
__device__ __forceinline__ void gemm_body(const h16* __restrict__ A,
                                          const h16* __restrict__ Bt,
                                          const float* __restrict__ bias,
                                          h16* __restrict__ outh,
                                          float* __restrict__ outf,
                                          int mode) {
  constexpr int JT = BN / 32;  // j-tiles per wave
  __shared__ __align__(16) h16 As[128 * 32];
  __shared__ __align__(16) h16 Bs[BN * 32];
  const int tid = threadIdx.x;
  const int lane = tid & 63;
  const int w = tid >> 6;
  const int wm = w >> 1, wn = w & 1;
  const int cl = lane & 15, s = lane >> 4;
  const int m0 = blockIdx.x * 128;
  const int n0 = blockIdx.y * BN;
  const int lr = lane >> 2, lg = lane & 3;

  const f32x4 zero = {0.f, 0.f, 0.f, 0.f};
  f32x4 acc[4][JT];
#pragma unroll
  for (int i = 0; i < 4; i++)
#pragma unroll
    for (int j = 0; j < JT; j++) acc[i][j] = zero;

  const h16* aw = A + (size_t)(m0 + w * 32) * D_MODEL;
  const h16* bw = Bt + (size_t)(n0 + w * (BN / 4)) * D_MODEL;

  for (int k0 = 0; k0 < D_MODEL; k0 += 32) {
#pragma unroll
    for (int issue = 0; issue < 2; issue++) {
      GLD16(aw + (size_t)(issue * 16 + lr) * D_MODEL + k0 + lg * 8,
            As + (w * 32 + issue * 16) * 32);
    }
    if (BN == 128) {
#pragma unroll
      for (int issue = 0; issue < 2; issue++)
        GLD16(bw + (size_t)(issue * 16 + lr) * D_MODEL + k0 + lg * 8,
              Bs + (w * 32 + issue * 16) * 32);
    } else {
      GLD16(bw + (size_t)lr * D_MODEL + k0 + lg * 8, Bs + (w * 16) * 32);
    }
    __syncthreads();
    half8 af[4], bf[JT];
#pragma unroll
    for (int i = 0; i < 4; i++)
      af[i] = *reinterpret_cast<const half8*>(As + (wm * 64 + i * 16 + cl) * 32 + s * 8);
#pragma unroll
    for (int j = 0; j < JT; j++)
      bf[j] = *reinterpret_cast<const half8*>(Bs + (wn * (BN / 2) + j * 16 + cl) * 32 + s * 8);
    __builtin_amdgcn_s_setprio(1);
#pragma unroll
    for (int i = 0; i < 4; i++)
#pragma unroll
      for (int j = 0; j < JT; j++)
        acc[i][j] = __builtin_amdgcn_mfma_f32_16x16x32_f16(af[i], bf[j], acc[i][j], 0, 0, 0);
    __builtin_amdgcn_s_setprio(0);
    __syncthreads();
  }

#pragma unroll
  for (int i = 0; i < 4; i++)
#pragma unroll
    for (int j = 0; j < JT; j++) {
      int c = n0 + wn * (BN / 2) + j * 16 + cl;
      float bv = bias[c];
      int mb = m0 + wm * 64 + i * 16 + s * 4;
      if (mode == 0) {
#pragma unroll
        for (int r = 0; r < 4; r++)
          outh[(size_t)(mb + r) * D_MODEL + c] = (h16)(acc[i][j][r] + bv);
      } else if (mode == 1) {
        int b = mb >> 11, l = mb & 2047;
        int h = c >> 6, d = c & 63;
        half4 o = {(h16)(acc[i][j][0] + bv), (h16)(acc[i][j][1] + bv),
                   (h16)(acc[i][j][2] + bv), (h16)(acc[i][j][3] + bv)};
        *reinterpret_cast<half4*>(outh + (((size_t)(b * N_HEADS + h) * D_HEAD + d) * SEQ_L + l)) = o;
      } else if (mode == 3) {
#pragma unroll
        for (int r = 0; r < 4; r++) {
          int m = mb + r;
          int b = m >> 11, l = m & 2047;
          int h = c >> 6, d = c & 63;
          int dsw = (((d >> 3) ^ (l & 7)) << 3) | (d & 7);
          outh[((size_t)(b * N_HEADS + h) * SEQ_L + l) * D_HEAD + dsw] =
              (h16)(acc[i][j][r] + bv);
        }
      } else {
#pragma unroll
        for (int r = 0; r < 4; r++)
          outf[(size_t)(mb + r) * D_MODEL + c] = acc[i][j][r] + bv;
      }
    }
}

struct ProjArgs {
  const h16* A[3];
  const h16* W[3];
  const float* b[3];
  h16* out[3];
};

__global__ __launch_bounds__(256) void proj_kernel(ProjArgs pa) {
  int z = blockIdx.z;
  int mode = (z == 0) ? 0 : (z == 1) ? 3 : 1;
  gemm_body<128>(pa.A[z], pa.W[z], pa.b[z], pa.out[z], nullptr, mode);
}

__global__ __launch_bounds__(256) void out_kernel(const h16* __restrict__ A,
                                                  const h16* __restrict__ Wt,
                                                  const float* __restrict__ b,
                                                  float* __restrict__ out) {
  gemm_body<64>(A, Wt, b, nullptr, out, 2);
}

// ---------------------------------------------------------------------------
// Flash attention. grid 1024 (XCD-remapped), 4 waves, 16 q-rows/wave (QBLK=64).
// K staged via global_load_lds from PRE-SWIZZLED Kh (swizzle baked in global);
// V read direct from global V^T (L2-resident); P via wave-private LDS (4KB).
// LDS = 16KB K + 16KB P = 32KB -> 4 blocks/CU. Scores in exp2 units.
// ---------------------------------------------------------------------------
__global__ __launch_bounds__(256) void attn_kernel(const h16* __restrict__ Qh,
                                                   const h16* __restrict__ Kh,
                                                   const h16* __restrict__ Vt,
                                                   h16* __restrict__ ctx) {
  __shared__ __align__(16) char Ks[16384];   // [128 kv][64 d] pre-swizzled rows
  __shared__ __align__(16) char Ps[16384];   // 4 waves x [16 q][128 kv]
  const int tid = threadIdx.x;
  const int lane = tid & 63;
  const int w = tid >> 6;
  char* Pw = Ps + w * 4096;
  // XCD-aware remap: xcd owns bh in [4*xcd, 4*xcd+4), 32 qtiles each
  int lid = blockIdx.x;
  int xcd = lid & 7, slot = lid >> 3;
  int bh = xcd * 4 + (slot & 3);
  int qt = slot >> 2;
  const int b = bh >> 4, h = bh & 15;
  const int q0 = qt * 64 + w * 16;
  const int cl = lane & 15, s = lane >> 4;

  const h16* Kb = Kh + (size_t)bh * SEQ_L * D_HEAD;   // swizzled [l][64]
  const h16* Vb = Vt + (size_t)bh * D_HEAD * SEQ_L;   // [d][kv]

  // hoist Q fragments: row q0+cl, k granule kk*32 + s*8
  half8 qf[2];
#pragma unroll
  for (int kk = 0; kk < 2; kk++)
    qf[kk] = *reinterpret_cast<const half8*>(
        Qh + (size_t)(b * SEQ_L + q0 + cl) * D_MODEL + h * D_HEAD + kk * 32 + s * 8);

  const f32x4 zero = {0.f, 0.f, 0.f, 0.f};
  f32x4 acc[4];
#pragma unroll
  for (int td = 0; td < 4; td++) acc[td] = zero;
  float mrow[4], lrow[4];
#pragma unroll
  for (int rg = 0; rg < 4; rg++) { mrow[rg] = -INFINITY; lrow[rg] = 0.f; }

  for (int kv0 = 0; kv0 < SEQ_L; kv0 += 128) {
    // ---- stage K tile async: wave w stages rows w*32..w*32+31, 4x 1KB ----
#pragma unroll
    for (int issue = 0; issue < 4; issue++) {
      GLD16(Kb + (size_t)(kv0 + w * 32 + issue * 8) * D_HEAD + lane * 8,
            (h16*)Ks + (w * 32 + issue * 8) * D_HEAD);
    }
    __syncthreads();

    // ---- QK^T: S[16 q][128 kv] ----
    f32x4 sc[8];
#pragma unroll
    for (int t = 0; t < 8; t++) {
      int r = t * 16 + cl;
      half8 bf0 = *reinterpret_cast<const half8*>(Ks + r * 128 + ((s ^ (r & 7)) << 4));
      half8 bf1 = *reinterpret_cast<const half8*>(Ks + r * 128 + (((4 + s) ^ (r & 7)) << 4));
      __builtin_amdgcn_s_setprio(1);
      sc[t] = __builtin_amdgcn_mfma_f32_16x16x32_f16(qf[0], bf0, zero, 0, 0, 0);
      sc[t] = __builtin_amdgcn_mfma_f32_16x16x32_f16(qf[1], bf1, sc[t], 0, 0, 0);
      __builtin_amdgcn_s_setprio(0);
    }

    // ---- online softmax, exp2 units, defer-rescale (rows pr = s*4+rg) ----
    float ml[4];
    bool cok = true;
#pragma unroll
    for (int rg = 0; rg < 4; rg++) {
      float m = sc[0][rg];
#pragma unroll
      for (int t = 1; t < 8; t++) m = fmaxf(m, sc[t][rg]);
#pragma unroll
      for (int msk = 1; msk < 16; msk <<= 1) m = fmaxf(m, __shfl_xor(m, msk));
      ml[rg] = m;
      cok = cok && (m <= mrow[rg] + DEFER_TH);
    }
    if (!__all(cok)) {
#pragma unroll
      for (int rg = 0; rg < 4; rg++) {
        float mn = fmaxf(mrow[rg], ml[rg]);
        float al = exp2f(mrow[rg] - mn);
        mrow[rg] = mn;
        lrow[rg] *= al;
#pragma unroll
        for (int td = 0; td < 4; td++) acc[td][rg] *= al;
      }
    }
#pragma unroll
    for (int rg = 0; rg < 4; rg++) {
      float rs = 0.f;
      int pr = s * 4 + rg;
      int swz = ((s & 3) << 5) ^ ((rg & 1) << 7);
#pragma unroll
      for (int t = 0; t < 8; t++) {
        float p = exp2f(sc[t][rg] - mrow[rg]);
        rs += p;
        int pc = t * 16 + cl;
        *reinterpret_cast<h16*>(Pw + pr * 256 + ((pc * 2) ^ swz)) = (h16)p;
      }
#pragma unroll
      for (int msk = 1; msk < 16; msk <<= 1) rs += __shfl_xor(rs, msk);
      lrow[rg] += rs;
    }

    // ---- PV: P from LDS (pr = cl), V direct from global V^T ----
#pragma unroll
    for (int kvs = 0; kvs < 4; kvs++) {
      half8 pf = *reinterpret_cast<const half8*>(
          Pw + cl * 256 + ((((kvs * 4 + s) << 4) ^ (((cl >> 2) & 3) << 5)) ^ ((cl & 1) << 7)));
      const h16* Vg = Vb + kv0 + kvs * 32 + s * 8;
#pragma unroll
      for (int td = 0; td < 4; td++) {
        half8 vf = *reinterpret_cast<const half8*>(Vg + (size_t)(td * 16 + cl) * SEQ_L);
        __builtin_amdgcn_s_setprio(1);
        acc[td] = __builtin_amdgcn_mfma_f32_16x16x32_f16(pf, vf, acc[td], 0, 0, 0);
        __builtin_amdgcn_s_setprio(0);
      }
    }
    __syncthreads();
  }

  // ---- write ctx f16 natural [b*L + q][h*64 + d] ----
#pragma unroll
  for (int td = 0; td < 4; td++)
#pragma unroll
    for (int rg = 0; rg < 4; rg++) {
      int row = q0 + s * 4 + rg;
      int d = td * 16 + cl;
      float v = acc[td][rg] / lrow[rg];
      ctx[(size_t)(b * SEQ_L + row) * D_MODEL + h * D_HEAD + d] = (h16)v;
    }
}

// ---------------------------------------------------------------------------
extern "C" void kernel_launch(void* const* d_in, const int* in_sizes, int n_in,
                              void* d_out, int out_size, void* d_ws, size_t ws_size,
                              hipStream_t stream) {
  const float* Q = (const float*)d_in[0];
  const float* K = (const float*)d_in[1];
  const float* V = (const float*)d_in[2];
  const float* Wq = (const float*)d_in[3];
  const float* bq = (const float*)d_in[4];
  const float* Wk = (const float*)d_in[5];
  const float* bk = (const float*)d_in[6];
  const float* Wv = (const float*)d_in[7];
  const float* bv = (const float*)d_in[8];
  const float* Wo = (const float*)d_in[9];
  const float* bo = (const float*)d_in[10];
  float* out = (float*)d_out;

  char* ws = (char*)d_ws;
  const size_t MB = 1024 * 1024;
  h16* Xh[3] = {(h16*)(ws), (h16*)(ws + 8 * MB), (h16*)(ws + 16 * MB)};
  h16* Wt[4] = {(h16*)(ws + 24 * MB), (h16*)(ws + 26 * MB),
                (h16*)(ws + 28 * MB), (h16*)(ws + 30 * MB)};
  h16* Qh = (h16*)(ws + 32 * MB);
  h16* Kh = (h16*)(ws + 40 * MB);
  h16* Vt = (h16*)(ws + 48 * MB);
  float* bqs = (float*)(ws + 56 * MB);
  h16* ctx = Xh[0];  // Xh[0] dead after projections

  XArgs xa;
  xa.src[0] = Q; xa.src[1] = K; xa.src[2] = V;
  xa.dst[0] = Xh[0]; xa.dst[1] = Xh[1]; xa.dst[2] = Xh[2];
  convert_x<<<dim3(2048, 3), 256, 0, stream>>>(xa);

  WArgs wa;
  wa.w[0] = Wq; wa.w[1] = Wk; wa.w[2] = Wv; wa.w[3] = Wo;
  wa.wt[0] = Wt[0]; wa.wt[1] = Wt[1]; wa.wt[2] = Wt[2]; wa.wt[3] = Wt[3];
  convert_wt<<<dim3(16, 16, 4), 256, 0, stream>>>(wa);
  convert_bq<<<dim3(4), 256, 0, stream>>>(bq, bqs);

  ProjArgs pa;
  pa.A[0] = Xh[0]; pa.A[1] = Xh[1]; pa.A[2] = Xh[2];
  pa.W[0] = Wt[0]; pa.W[1] = Wt[1]; pa.W[2] = Wt[2];
  pa.b[0] = bqs;   pa.b[1] = bk;    pa.b[2] = bv;
  pa.out[0] = Qh;  pa.out[1] = Kh;  pa.out[2] = Vt;
  proj_kernel<<<dim3(32, 8, 3), 256, 0, stream>>>(pa);

  attn_kernel<<<dim3(1024), 256, 0, stream>>>(Qh, Kh, Vt, ctx);

  out_kernel<<<dim3(32, 16), 256, 0, stream>>>(ctx, Wt[3], bo, out);
}

// Round 7
// 190.086 us; speedup vs baseline: 1.6914x; 1.1553x over previous
//
#include <hip/hip_runtime.h>

// MHA: out = softmax((XWq)(XWk)^T/8)(XWv) Wo ; B=2, L=2048, D=1024, H=16, dk=64
// fp32 in/out, f16 MFMA internally, f32 accumulation.

typedef _Float16 h16;
typedef _Float16 half8 __attribute__((ext_vector_type(8)));
typedef _Float16 half4 __attribute__((ext_vector_type(4)));
typedef float f32x4 __attribute__((ext_vector_type(4)));

#define D_MODEL 1024
#define N_HEADS 16
#define D_HEAD  64
#define SEQ_L   2048
// fold 1/sqrt(dk) and log2(e) into Wq so scores are in exp2 units
#define QSCALE   0.18033688011f
#define DEFER_TH 10.0f  // exp2 units; P bounded by 2^10=1024 (f16-safe)

// async global->LDS, 16B per lane, wave-uniform LDS base (HW adds lane*16)
#define GLD16(gp, lp)                                                  \
  __builtin_amdgcn_global_load_lds(                                    \
      (const __attribute__((address_space(1))) void*)(gp),             \
      (__attribute__((address_space(3))) void*)(lp), 16, 0, 0)

// ---------------------------------------------------------------------------
// conversion kernels
// ---------------------------------------------------------------------------
struct XArgs { const float* src[3]; h16* dst[3]; };

__global__ __launch_bounds__(256) void convert_x(XArgs xa) {
  const float* src = xa.src[blockIdx.y];
  h16* dst = xa.dst[blockIdx.y];
  size_t i = ((size_t)blockIdx.x * 256 + threadIdx.x) * 8;
  float4 a = *reinterpret_cast<const float4*>(src + i);
  float4 b = *reinterpret_cast<const float4*>(src + i + 4);
  half8 o = {(h16)a.x, (h16)a.y, (h16)a.z, (h16)a.w,
             (h16)b.x, (h16)b.y, (h16)b.z, (h16)b.w};
  *reinterpret_cast<half8*>(dst + i) = o;
}

struct WArgs { const float* w[4]; h16* wt[4]; };

__global__ __launch_bounds__(256) void convert_wt(WArgs wa) {
  int z = blockIdx.z;
  const float* W = wa.w[z];
  h16* Wt = wa.wt[z];
  float scale = (z == 0) ? QSCALE : 1.0f;
  int k0 = blockIdx.x * 64, n0 = blockIdx.y * 64;
  __shared__ h16 T[64][65];
  int tid = threadIdx.x;
#pragma unroll
  for (int q = 0; q < 4; q++) {
    int fi = q * 256 + tid;
    int r = fi >> 4, c4 = (fi & 15) * 4;
    float4 v = *reinterpret_cast<const float4*>(W + (size_t)(k0 + r) * D_MODEL + n0 + c4);
    T[c4 + 0][r] = (h16)(v.x * scale);
    T[c4 + 1][r] = (h16)(v.y * scale);
    T[c4 + 2][r] = (h16)(v.z * scale);
    T[c4 + 3][r] = (h16)(v.w * scale);
  }
  __syncthreads();
#pragma unroll
  for (int q = 0; q < 2; q++) {
    int fi = q * 256 + tid;
    int r = fi >> 3, g = fi & 7;
    half8 o;
#pragma unroll
    for (int j = 0; j < 8; j++) o[j] = T[r][g * 8 + j];
    *reinterpret_cast<half8*>(Wt + (size_t)(n0 + r) * D_MODEL + k0 + g * 8) = o;
  }
}

__global__ __launch_bounds__(256) void convert_bq(const float* bq, float* bqs) {
  int i = blockIdx.x * 256 + threadIdx.x;
  if (i < D_MODEL) bqs[i] = bq[i] * QSCALE;
}

// ---------------------------------------------------------------------------
// f16 GEMM: 128xBN tile, BK=32, global_load_lds x16B, linear LDS (64B rows),
// 4 waves (2x2). Each wave stages BN/4 B-rows (global row base n0 + w*(BN/4)).
// mode 0: f16 natural [m][n]
// mode 1: f16 V^T [b][h][d][L], kv-swizzled: element [d][l] at l^((d&7)<<3)
// mode 2: f32 natural
// mode 3: f16 K pre-swizzled [b][h][l][64], element d at ((d>>3)^(l&7))*8+(d&7)
// ---------------------------------------------------------------------------
template <int BN>
__device__ __forceinline__ void gemm_body(const h16* __restrict__ A,
                                          const h16* __restrict__ Bt,
                                          const float* __restrict__ bias,
                                          h16* __restrict__ outh,
                                          float* __restrict__ outf,
                                          int mode) {
  constexpr int JT = BN / 32;  // j-tiles per wave
  __shared__ __align__(16) h16 As[128 * 32];
  __shared__ __align__(16) h16 Bs[BN * 32];
  const int tid = threadIdx.x;
  const int lane = tid & 63;
  const int w = tid >> 6;
  const int wm = w >> 1, wn = w & 1;
  const int cl = lane & 15, s = lane >> 4;
  const int m0 = blockIdx.x * 128;
  const int n0 = blockIdx.y * BN;
  const int lr = lane >> 2, lg = lane & 3;

  const f32x4 zero = {0.f, 0.f, 0.f, 0.f};
  f32x4 acc[4][JT];
#pragma unroll
  for (int i = 0; i < 4; i++)
#pragma unroll
    for (int j = 0; j < JT; j++) acc[i][j] = zero;

  const h16* aw = A + (size_t)(m0 + w * 32) * D_MODEL;
  const h16* bw = Bt + (size_t)(n0 + w * (BN / 4)) * D_MODEL;

  for (int k0 = 0; k0 < D_MODEL; k0 += 32) {
#pragma unroll
    for (int issue = 0; issue < 2; issue++) {
      GLD16(aw + (size_t)(issue * 16 + lr) * D_MODEL + k0 + lg * 8,
            As + (w * 32 + issue * 16) * 32);
    }
    if (BN == 128) {
#pragma unroll
      for (int issue = 0; issue < 2; issue++)
        GLD16(bw + (size_t)(issue * 16 + lr) * D_MODEL + k0 + lg * 8,
              Bs + (w * 32 + issue * 16) * 32);
    } else {
      GLD16(bw + (size_t)lr * D_MODEL + k0 + lg * 8, Bs + (w * 16) * 32);
    }
    __syncthreads();
    half8 af[4], bf[JT];
#pragma unroll
    for (int i = 0; i < 4; i++)
      af[i] = *reinterpret_cast<const half8*>(As + (wm * 64 + i * 16 + cl) * 32 + s * 8);
#pragma unroll
    for (int j = 0; j < JT; j++)
      bf[j] = *reinterpret_cast<const half8*>(Bs + (wn * (BN / 2) + j * 16 + cl) * 32 + s * 8);
    __builtin_amdgcn_s_setprio(1);
#pragma unroll
    for (int i = 0; i < 4; i++)
#pragma unroll
      for (int j = 0; j < JT; j++)
        acc[i][j] = __builtin_amdgcn_mfma_f32_16x16x32_f16(af[i], bf[j], acc[i][j], 0, 0, 0);
    __builtin_amdgcn_s_setprio(0);
    __syncthreads();
  }

#pragma unroll
  for (int i = 0; i < 4; i++)
#pragma unroll
    for (int j = 0; j < JT; j++) {
      int c = n0 + wn * (BN / 2) + j * 16 + cl;
      float bv = bias[c];
      int mb = m0 + wm * 64 + i * 16 + s * 4;
      if (mode == 0) {
#pragma unroll
        for (int r = 0; r < 4; r++)
          outh[(size_t)(mb + r) * D_MODEL + c] = (h16)(acc[i][j][r] + bv);
      } else if (mode == 1) {
        int b = mb >> 11, l = mb & 2047;
        int h = c >> 6, d = c & 63;
        int lsw = l ^ ((d & 7) << 3);  // bake attn V-LDS swizzle into global
        half4 o = {(h16)(acc[i][j][0] + bv), (h16)(acc[i][j][1] + bv),
                   (h16)(acc[i][j][2] + bv), (h16)(acc[i][j][3] + bv)};
        *reinterpret_cast<half4*>(outh + (((size_t)(b * N_HEADS + h) * D_HEAD + d) * SEQ_L + lsw)) = o;
      } else if (mode == 3) {
#pragma unroll
        for (int r = 0; r < 4; r++) {
          int m = mb + r;
          int b = m >> 11, l = m & 2047;
          int h = c >> 6, d = c & 63;
          int dsw = (((d >> 3) ^ (l & 7)) << 3) | (d & 7);
          outh[((size_t)(b * N_HEADS + h) * SEQ_L + l) * D_HEAD + dsw] =
              (h16)(acc[i][j][r] + bv);
        }
      } else {
#pragma unroll
        for (int r = 0; r < 4; r++)
          outf[(size_t)(mb + r) * D_MODEL + c] = acc[i][j][r] + bv;
      }
    }
}

struct ProjArgs {
  const h16* A[3];
  const h16* W[3];
  const float* b[3];
  h16* out[3];
};

__global__ __launch_bounds__(256) void proj_kernel(ProjArgs pa) {
  int z = blockIdx.z;
  int mode = (z == 0) ? 0 : (z == 1) ? 3 : 1;
  gemm_body<128>(pa.A[z], pa.W[z], pa.b[z], pa.out[z], nullptr, mode);
}

__global__ __launch_bounds__(256) void out_kernel(const h16* __restrict__ A,
                                                  const h16* __restrict__ Wt,
                                                  const float* __restrict__ b,
                                                  float* __restrict__ out) {
  gemm_body<64>(A, Wt, b, nullptr, out, 2);
}

// ---------------------------------------------------------------------------
// Flash attention. grid 1024 (XCD-remapped), 4 waves, 16 q-rows/wave (QBLK=64).
// K AND V staged via global_load_lds from PRE-SWIZZLED global layouts (zero
// staging VALU/VGPR); P via wave-private LDS. LDS = 16K K + 16V + 16P = 48KB
// -> 3 blocks/CU. Scores in exp2 units.
// ---------------------------------------------------------------------------
__global__ __launch_bounds__(256, 4) void attn_kernel(const h16* __restrict__ Qh,
                                                      const h16* __restrict__ Kh,
                                                      const h16* __restrict__ Vt,
                                                      h16* __restrict__ ctx) {
  __shared__ __align__(16) char smem[49152];
  char* Ks = smem;            // [128 kv][64 d] pre-swizzled rows (128B)
  char* Vs = smem + 16384;    // [64 d][128 kv] pre-swizzled rows (256B)
  char* Ps = smem + 32768;    // 4 waves x [16 q][128 kv]
  const int tid = threadIdx.x;
  const int lane = tid & 63;
  const int w = tid >> 6;
  char* Pw = Ps + w * 4096;
  // XCD-aware remap: xcd owns bh in [4*xcd, 4*xcd+4), 32 qtiles each
  int lid = blockIdx.x;
  int xcd = lid & 7, slot = lid >> 3;
  int bh = xcd * 4 + (slot & 3);
  int qt = slot >> 2;
  const int b = bh >> 4, h = bh & 15;
  const int q0 = qt * 64 + w * 16;
  const int cl = lane & 15, s = lane >> 4;

  const h16* Kb = Kh + (size_t)bh * SEQ_L * D_HEAD;   // swizzled [l][64]
  const h16* Vb = Vt + (size_t)bh * D_HEAD * SEQ_L;   // swizzled [d][kv]

  // hoist Q fragments: row q0+cl, k granule kk*32 + s*8
  half8 qf[2];
#pragma unroll
  for (int kk = 0; kk < 2; kk++)
    qf[kk] = *reinterpret_cast<const half8*>(
        Qh + (size_t)(b * SEQ_L + q0 + cl) * D_MODEL + h * D_HEAD + kk * 32 + s * 8);

  const f32x4 zero = {0.f, 0.f, 0.f, 0.f};
  f32x4 acc[4];
#pragma unroll
  for (int td = 0; td < 4; td++) acc[td] = zero;
  float mrow[4], lrow[4];
#pragma unroll
  for (int rg = 0; rg < 4; rg++) { mrow[rg] = -INFINITY; lrow[rg] = 0.f; }

  for (int kv0 = 0; kv0 < SEQ_L; kv0 += 128) {
    // ---- stage K tile async: wave w stages kv-rows w*32..w*32+31 ----
#pragma unroll
    for (int issue = 0; issue < 4; issue++) {
      GLD16(Kb + (size_t)(kv0 + w * 32 + issue * 8) * D_HEAD + lane * 8,
            (h16*)Ks + (w * 32 + issue * 8) * D_HEAD);
    }
    // ---- stage V tile async: wave w stages d-rows w*16..w*16+15 ----
#pragma unroll
    for (int issue = 0; issue < 4; issue++) {
      GLD16(Vb + (size_t)(w * 16 + issue * 4 + (lane >> 4)) * SEQ_L + kv0 + (lane & 15) * 8,
            (h16*)Vs + (w * 16 + issue * 4) * 128);
    }
    __syncthreads();

    // ---- QK^T: S[16 q][128 kv] ----
    f32x4 sc[8];
#pragma unroll
    for (int t = 0; t < 8; t++) {
      int r = t * 16 + cl;
      half8 bf0 = *reinterpret_cast<const half8*>(Ks + r * 128 + ((s ^ (r & 7)) << 4));
      half8 bf1 = *reinterpret_cast<const half8*>(Ks + r * 128 + (((4 + s) ^ (r & 7)) << 4));
      __builtin_amdgcn_s_setprio(1);
      sc[t] = __builtin_amdgcn_mfma_f32_16x16x32_f16(qf[0], bf0, zero, 0, 0, 0);
      sc[t] = __builtin_amdgcn_mfma_f32_16x16x32_f16(qf[1], bf1, sc[t], 0, 0, 0);
      __builtin_amdgcn_s_setprio(0);
    }

    // ---- online softmax, exp2 units, defer-rescale (rows pr = s*4+rg) ----
    float ml[4];
    bool cok = true;
#pragma unroll
    for (int rg = 0; rg < 4; rg++) {
      float m = sc[0][rg];
#pragma unroll
      for (int t = 1; t < 8; t++) m = fmaxf(m, sc[t][rg]);
#pragma unroll
      for (int msk = 1; msk < 16; msk <<= 1) m = fmaxf(m, __shfl_xor(m, msk));
      ml[rg] = m;
      cok = cok && (m <= mrow[rg] + DEFER_TH);
    }
    if (!__all(cok)) {
#pragma unroll
      for (int rg = 0; rg < 4; rg++) {
        float mn = fmaxf(mrow[rg], ml[rg]);
        float al = exp2f(mrow[rg] - mn);
        mrow[rg] = mn;
        lrow[rg] *= al;
#pragma unroll
        for (int td = 0; td < 4; td++) acc[td][rg] *= al;
      }
    }
#pragma unroll
    for (int rg = 0; rg < 4; rg++) {
      float rs = 0.f;
      int pr = s * 4 + rg;
      int swz = ((s & 3) << 5) ^ ((rg & 1) << 7);
#pragma unroll
      for (int t = 0; t < 8; t++) {
        float p = exp2f(sc[t][rg] - mrow[rg]);
        rs += p;
        int pc = t * 16 + cl;
        *reinterpret_cast<h16*>(Pw + pr * 256 + ((pc * 2) ^ swz)) = (h16)p;
      }
#pragma unroll
      for (int msk = 1; msk < 16; msk <<= 1) rs += __shfl_xor(rs, msk);
      lrow[rg] += rs;
    }

    // ---- PV: P from LDS (pr = cl), V from LDS (swizzled rows) ----
#pragma unroll
    for (int kvs = 0; kvs < 4; kvs++) {
      half8 pf = *reinterpret_cast<const half8*>(
          Pw + cl * 256 + ((((kvs * 4 + s) << 4) ^ (((cl >> 2) & 3) << 5)) ^ ((cl & 1) << 7)));
#pragma unroll
      for (int td = 0; td < 4; td++) {
        int d = td * 16 + cl;
        half8 vf = *reinterpret_cast<const half8*>(
            Vs + d * 256 + (((kvs * 4 + s) ^ (d & 7)) << 4));
        __builtin_amdgcn_s_setprio(1);
        acc[td] = __builtin_amdgcn_mfma_f32_16x16x32_f16(pf, vf, acc[td], 0, 0, 0);
        __builtin_amdgcn_s_setprio(0);
      }
    }
    __syncthreads();
  }

  // ---- write ctx f16 natural [b*L + q][h*64 + d] ----
#pragma unroll
  for (int td = 0; td < 4; td++)
#pragma unroll
    for (int rg = 0; rg < 4; rg++) {
      int row = q0 + s * 4 + rg;
      int d = td * 16 + cl;
      float v = acc[td][rg] / lrow[rg];
      ctx[(size_t)(b * SEQ_L + row) * D_MODEL + h * D_HEAD + d] = (h16)v;
    }
}

// ---------------------------------------------------------------------------
extern "C" void kernel_launch(void* const* d_in, const int* in_sizes, int n_in,
                              void* d_out, int out_size, void* d_ws, size_t ws_size,
                              hipStream_t stream) {
  const float* Q = (const float*)d_in[0];
  const float* K = (const float*)d_in[1];
  const float* V = (const float*)d_in[2];
  const float* Wq = (const float*)d_in[3];
  const float* bq = (const float*)d_in[4];
  const float* Wk = (const float*)d_in[5];
  const float* bk = (const float*)d_in[6];
  const float* Wv = (const float*)d_in[7];
  const float* bv = (const float*)d_in[8];
  const float* Wo = (const float*)d_in[9];
  const float* bo = (const float*)d_in[10];
  float* out = (float*)d_out;

  char* ws = (char*)d_ws;
  const size_t MB = 1024 * 1024;
  h16* Xh[3] = {(h16*)(ws), (h16*)(ws + 8 * MB), (h16*)(ws + 16 * MB)};
  h16* Wt[4] = {(h16*)(ws + 24 * MB), (h16*)(ws + 26 * MB),
                (h16*)(ws + 28 * MB), (h16*)(ws + 30 * MB)};
  h16* Qh = (h16*)(ws + 32 * MB);
  h16* Kh = (h16*)(ws + 40 * MB);
  h16* Vt = (h16*)(ws + 48 * MB);
  float* bqs = (float*)(ws + 56 * MB);
  h16* ctx = Xh[0];  // Xh[0] dead after projections

  XArgs xa;
  xa.src[0] = Q; xa.src[1] = K; xa.src[2] = V;
  xa.dst[0] = Xh[0]; xa.dst[1] = Xh[1]; xa.dst[2] = Xh[2];
  convert_x<<<dim3(2048, 3), 256, 0, stream>>>(xa);

  WArgs wa;
  wa.w[0] = Wq; wa.w[1] = Wk; wa.w[2] = Wv; wa.w[3] = Wo;
  wa.wt[0] = Wt[0]; wa.wt[1] = Wt[1]; wa.wt[2] = Wt[2]; wa.wt[3] = Wt[3];
  convert_wt<<<dim3(16, 16, 4), 256, 0, stream>>>(wa);
  convert_bq<<<dim3(4), 256, 0, stream>>>(bq, bqs);

  ProjArgs pa;
  pa.A[0] = Xh[0]; pa.A[1] = Xh[1]; pa.A[2] = Xh[2];
  pa.W[0] = Wt[0]; pa.W[1] = Wt[1]; pa.W[2] = Wt[2];
  pa.b[0] = bqs;   pa.b[1] = bk;    pa.b[2] = bv;
  pa.out[0] = Qh;  pa.out[1] = Kh;  pa.out[2] = Vt;
  proj_kernel<<<dim3(32, 8, 3), 256, 0, stream>>>(pa);

  attn_kernel<<<dim3(1024), 256, 0, stream>>>(Qh, Kh, Vt, ctx);

  out_kernel<<<dim3(32, 16), 256, 0, stream>>>(ctx, Wt[3], bo, out);
}